// Round 1
// baseline (327.621 us; speedup 1.0000x reference)
//
#include <hip/hip_runtime.h>

#define NB 32
#define CCH 128
#define HH 56
#define WWD 56
#define HWP (HH*WWD)   // 3136
#define K3C (3*CCH)    // 384

typedef _Float16 half8 __attribute__((ext_vector_type(8)));
typedef float floatx4 __attribute__((ext_vector_type(4)));

// ---------------- t8 kernel: t8[n,o,p] = sum_c conv_w[o,c]*p5w[c]*x[n,c,roll(p)] ----------------
__global__ __launch_bounds__(256) void t8_kernel(const float* __restrict__ x,
                                                 const float* __restrict__ conv_w,
                                                 const float* __restrict__ p5w,
                                                 float* __restrict__ t8) {
    int idx = blockIdx.x * 256 + threadIdx.x;
    if (idx >= NB * 4 * HWP) return;
    int p  = idx % HWP;
    int no = idx / HWP;
    int o  = no & 3;
    int nb = no >> 2;
    int proll = (p >= WWD) ? (p - WWD) : (p + (HH - 1) * WWD);
    const float* xb = x + (size_t)nb * CCH * HWP + proll;
    float acc = 0.f;
#pragma unroll 8
    for (int c = 0; c < CCH; ++c)
        acc += conv_w[o * CCH + c] * p5w[c] * xb[(size_t)c * HWP];
    t8[idx] = acc;
}

// ---------------- GEMM1: t7T[n, c2, k] = (1/56) * sum_p t2[n,k,p] * t6[n,c2,p] (f16 out) --------
__global__ __launch_bounds__(256) void gemm1_kernel(const float* __restrict__ x,
                                                    const float* __restrict__ p2w,
                                                    _Float16* __restrict__ t7T) {
    __shared__ _Float16 As[64 * 40];
    __shared__ _Float16 Bs[64 * 40];

    const int n  = blockIdx.z;
    const int m0 = blockIdx.x * 64;   // k-row base (0..383)
    const int n0 = blockIdx.y * 64;   // c2 base (0..127)
    const int tid = threadIdx.x;

    // staging map: 64 rows x 32 p; thread -> (row, 8-elem segment)
    const int srow = tid >> 2;          // 0..63
    const int sseg = (tid & 3) * 8;     // 0,8,16,24

    // A row meta: k = 3c + j; t2[k,p] = p2w[k,p] * x[c, p + 112*(j-1)] (zero pad)
    const int krow = m0 + srow;
    const int ca   = krow / 3;
    const int ja   = krow - ca * 3;
    const float* xa = x + ((size_t)n * CCH + ca) * HWP;
    const float* pw = p2w + (size_t)krow * HWP;
    const int ashift = 112 * (ja - 1);

    // B row meta: t6[c2,p] = x[c2,p] + x[c2, roll(p)]
    const int c2r = n0 + srow;
    const float* xb = x + ((size_t)n * CCH + c2r) * HWP;

    const int wave = tid >> 6;
    const int lane = tid & 63;
    const int l15  = lane & 15;
    const int quad = lane >> 4;
    const int wm   = (wave >> 1) * 32;
    const int wn   = (wave & 1) * 32;

    floatx4 acc00 = {0.f,0.f,0.f,0.f}, acc01 = {0.f,0.f,0.f,0.f};
    floatx4 acc10 = {0.f,0.f,0.f,0.f}, acc11 = {0.f,0.f,0.f,0.f};

    for (int p0 = 0; p0 < HWP; p0 += 32) {
        const int pA   = p0 + sseg;
        // ---- stage A ----
        {
            float fa[8];
            const int srcp = pA + ashift;   // 8-aligned; run is wholly in or out
            if (srcp >= 0 && srcp < HWP) {
                const float4 x0 = *(const float4*)(xa + srcp);
                const float4 x1 = *(const float4*)(xa + srcp + 4);
                const float4 w0 = *(const float4*)(pw + pA);
                const float4 w1 = *(const float4*)(pw + pA + 4);
                fa[0] = x0.x * w0.x; fa[1] = x0.y * w0.y; fa[2] = x0.z * w0.z; fa[3] = x0.w * w0.w;
                fa[4] = x1.x * w1.x; fa[5] = x1.y * w1.y; fa[6] = x1.z * w1.z; fa[7] = x1.w * w1.w;
            } else {
#pragma unroll
                for (int i = 0; i < 8; ++i) fa[i] = 0.f;
            }
            half8 av;
#pragma unroll
            for (int i = 0; i < 8; ++i) av[i] = (_Float16)fa[i];
            *(half8*)(&As[srow * 40 + sseg]) = av;
        }
        // ---- stage B ----
        {
            const int h = pA / WWD;                       // 8-runs never cross an h row
            const int proll = (h >= 1) ? (pA - WWD) : (pA + (HH - 1) * WWD);
            const float4 u0 = *(const float4*)(xb + pA);
            const float4 u1 = *(const float4*)(xb + pA + 4);
            const float4 v0 = *(const float4*)(xb + proll);
            const float4 v1 = *(const float4*)(xb + proll + 4);
            half8 bv;
            bv[0] = (_Float16)(u0.x + v0.x); bv[1] = (_Float16)(u0.y + v0.y);
            bv[2] = (_Float16)(u0.z + v0.z); bv[3] = (_Float16)(u0.w + v0.w);
            bv[4] = (_Float16)(u1.x + v1.x); bv[5] = (_Float16)(u1.y + v1.y);
            bv[6] = (_Float16)(u1.z + v1.z); bv[7] = (_Float16)(u1.w + v1.w);
            *(half8*)(&Bs[srow * 40 + sseg]) = bv;
        }
        __syncthreads();
        // ---- compute: each wave does a 32x32 quadrant = 2x2 MFMA tiles ----
        half8 a0 = *(half8*)(&As[(wm + l15) * 40 + quad * 8]);
        half8 a1 = *(half8*)(&As[(wm + 16 + l15) * 40 + quad * 8]);
        half8 b0 = *(half8*)(&Bs[(wn + l15) * 40 + quad * 8]);
        half8 b1 = *(half8*)(&Bs[(wn + 16 + l15) * 40 + quad * 8]);
        acc00 = __builtin_amdgcn_mfma_f32_16x16x32_f16(a0, b0, acc00, 0, 0, 0);
        acc01 = __builtin_amdgcn_mfma_f32_16x16x32_f16(a0, b1, acc01, 0, 0, 0);
        acc10 = __builtin_amdgcn_mfma_f32_16x16x32_f16(a1, b0, acc10, 0, 0, 0);
        acc11 = __builtin_amdgcn_mfma_f32_16x16x32_f16(a1, b1, acc11, 0, 0, 0);
        __syncthreads();
    }

    // epilogue: C/D layout col=lane&15 (c2), row=quad*4+reg (k). store t7T[c2][k] f16, scaled 1/56
    const float s = 1.0f / 56.0f;
    floatx4 accs[2][2] = {{acc00, acc01}, {acc10, acc11}};
#pragma unroll
    for (int mi = 0; mi < 2; ++mi)
#pragma unroll
        for (int ni = 0; ni < 2; ++ni) {
            const int kr = m0 + wm + mi * 16 + quad * 4;
            const int cc = n0 + wn + ni * 16 + l15;
            _Float16* dst = t7T + ((size_t)n * CCH + cc) * K3C + kr;
#pragma unroll
            for (int r = 0; r < 4; ++r) dst[r] = (_Float16)(accs[mi][ni][r] * s);
        }
}

// ---------------- GEMM2: out[n,c2,p] = t8[n,c2&3,p]*x[n,c2,p] + (1/sqrt(384)) sum_k t7T[c2,k]*t3[k,p]
__global__ __launch_bounds__(256) void gemm2_kernel(const float* __restrict__ x,
                                                    const _Float16* __restrict__ t7T,
                                                    const float* __restrict__ t8,
                                                    float* __restrict__ out) {
    __shared__ _Float16 As[64 * 40];   // [c2_local][k_local]
    __shared__ _Float16 Bs[64 * 40];   // [p_local][k_local]  (transposed t3 tile)

    const int n   = blockIdx.z;
    const int pt0 = blockIdx.x * 64;  // p base (0..3135)
    const int m0  = blockIdx.y * 64;  // c2 base (0..127)
    const int tid = threadIdx.x;

    // A staging: 64 rows (c2) x 32 k
    const int arow = tid >> 2;
    const int aseg = (tid & 3) * 8;
    const _Float16* asrc = t7T + ((size_t)n * CCH + (m0 + arow)) * K3C;

    // B staging: 32 k x 64 p (each thread: one k, 8 consecutive p)
    const int bk   = tid >> 3;        // 0..31
    const int bseg = (tid & 7) * 8;   // 0..56

    const int wave = tid >> 6;
    const int lane = tid & 63;
    const int l15  = lane & 15;
    const int quad = lane >> 4;
    const int wm   = (wave >> 1) * 32;
    const int wn   = (wave & 1) * 32;

    floatx4 acc00 = {0.f,0.f,0.f,0.f}, acc01 = {0.f,0.f,0.f,0.f};
    floatx4 acc10 = {0.f,0.f,0.f,0.f}, acc11 = {0.f,0.f,0.f,0.f};

    for (int k0 = 0; k0 < K3C; k0 += 32) {
        // ---- stage A (contiguous f16 copy) ----
        *(half8*)(&As[arow * 40 + aseg]) = *(const half8*)(asrc + k0 + aseg);
        // ---- stage B transposed: t3[k, p] = x[c, h, w + 2j - 2] (zero pad in w) ----
        {
            const int k  = k0 + bk;
            const int cb = k / 3;
            const int jb = k - cb * 3;
            const float* xrow = x + ((size_t)n * CCH + cb) * HWP;
            const int pg0 = pt0 + bseg;
            const int h   = pg0 / WWD;          // 8-run shares h (56 % 8 == 0)
            const int w0  = pg0 - h * WWD;
            const int shift = 2 * jb - 2;
            const float* xh = xrow + h * WWD;
#pragma unroll
            for (int i = 0; i < 8; ++i) {
                const int w = w0 + i + shift;
                const float v = (w >= 0 && w < WWD) ? xh[w] : 0.f;
                Bs[(bseg + i) * 40 + bk] = (_Float16)v;
            }
        }
        __syncthreads();
        half8 a0 = *(half8*)(&As[(wm + l15) * 40 + quad * 8]);
        half8 a1 = *(half8*)(&As[(wm + 16 + l15) * 40 + quad * 8]);
        half8 b0 = *(half8*)(&Bs[(wn + l15) * 40 + quad * 8]);
        half8 b1 = *(half8*)(&Bs[(wn + 16 + l15) * 40 + quad * 8]);
        acc00 = __builtin_amdgcn_mfma_f32_16x16x32_f16(a0, b0, acc00, 0, 0, 0);
        acc01 = __builtin_amdgcn_mfma_f32_16x16x32_f16(a0, b1, acc01, 0, 0, 0);
        acc10 = __builtin_amdgcn_mfma_f32_16x16x32_f16(a1, b0, acc10, 0, 0, 0);
        acc11 = __builtin_amdgcn_mfma_f32_16x16x32_f16(a1, b1, acc11, 0, 0, 0);
        __syncthreads();
    }

    // epilogue: row = c2 (quad*4+reg), col = p (lane&15); fuse t9 = t8[c2&3,p]*x[c2,p]
    const float s = 0.05103103630798288f;  // 1/sqrt(384)
    floatx4 accs[2][2] = {{acc00, acc01}, {acc10, acc11}};
#pragma unroll
    for (int mi = 0; mi < 2; ++mi)
#pragma unroll
        for (int ni = 0; ni < 2; ++ni) {
            const int ccb = m0 + wm + mi * 16 + quad * 4;
            const int pp  = pt0 + wn + ni * 16 + l15;
#pragma unroll
            for (int r = 0; r < 4; ++r) {
                const int c2 = ccb + r;
                const size_t oidx = ((size_t)n * CCH + c2) * HWP + pp;
                const float t9 = t8[((size_t)n * 4 + (c2 & 3)) * HWP + pp] * x[oidx];
                out[oidx] = accs[mi][ni][r] * s + t9;
            }
        }
}

extern "C" void kernel_launch(void* const* d_in, const int* in_sizes, int n_in,
                              void* d_out, int out_size, void* d_ws, size_t ws_size,
                              hipStream_t stream) {
    const float* x      = (const float*)d_in[0];
    const float* p2w    = (const float*)d_in[1];
    const float* p5w    = (const float*)d_in[2];
    const float* conv_w = (const float*)d_in[3];
    float* out = (float*)d_out;

    // workspace layout: t8 fp32 (1,605,632 B) then t7T f16 (3,145,728 B)
    float*    t8f = (float*)d_ws;
    _Float16* t7T = (_Float16*)((char*)d_ws + (size_t)NB * 4 * HWP * sizeof(float));

    t8_kernel<<<dim3((NB * 4 * HWP + 255) / 256), dim3(256), 0, stream>>>(x, conv_w, p5w, t8f);
    gemm1_kernel<<<dim3(6, 2, NB), dim3(256), 0, stream>>>(x, p2w, t7T);
    gemm2_kernel<<<dim3(49, 2, NB), dim3(256), 0, stream>>>(x, t7T, t8f, out);
}